// Round 6
// baseline (149.658 us; speedup 1.0000x reference)
//
#include <hip/hip_runtime.h>
#include <math.h>

typedef _Float16 f16x8 __attribute__((ext_vector_type(8)));
typedef _Float16 f16x2 __attribute__((ext_vector_type(2)));
typedef float    f32x4 __attribute__((ext_vector_type(4)));

union F16x8u { f16x8 v; f16x2 h[4]; };

// v_sin_f32 / v_cos_f32 take REVOLUTIONS: sin(2*pi*x) = v_sin(x).
__device__ __forceinline__ float cos1_hw(float x) { return __builtin_amdgcn_cosf(x); }
__device__ __forceinline__ float sin1_hw(float x) { return __builtin_amdgcn_sinf(x); }

// v_cvt_pkrtz_f16_f32 returns a __fp16 vector; bit-cast to our _Float16 pair.
__device__ __forceinline__ f16x2 pkrtz(float a, float b)
{
    return __builtin_bit_cast(f16x2, __builtin_amdgcn_cvt_pkrtz(a, b));
}

// ---------------------------------------------------------------------------
// ROUND 12 = RERUN of the round-11 timing diagnostic (round 11 died to an
// infra failure, not the kernel). Kernels byte-identical to round 10.
// The main kernel is launched 4x (idempotent: reads Frt/Fit/xnew, writes out
// with identical values). Purpose: dur_us = base + (extra launches) * k_main
// separates real kernel time k_main from fixed per-iteration overhead F,
// which three rounds of null results could not distinguish.
//   k_main = (dur_us - 87.1) / 6   [2-iteration model]
// Decision: ~330us -> kernel-bound (optimize kernel: ILP-2 + conj symmetry).
//           ~95-110us -> fixed-overhead-bound (minimal-dispatch structure).
// ---------------------------------------------------------------------------

// Pass 1: T[b][n2][k] = sum_n1 y[b,n1,n2] e^{-2pi i k n1/64}   (half2 r,i)
__global__ __launch_bounds__(256)
void dft_pass1(const float* __restrict__ y, f16x2* __restrict__ T)
{
    __shared__ float  YL[4096];
    __shared__ float2 tw[64];
    const int tid = threadIdx.x;
    const int b = blockIdx.x >> 3;
    const int g = blockIdx.x & 7;

    const float4* src = (const float4*)(y + (b << 12));
    float4* dst = (float4*)YL;
#pragma unroll
    for (int i = 0; i < 4; ++i) dst[tid + (i << 8)] = src[tid + (i << 8)];
    if (tid < 64) {
        const float a = (float)tid * (1.0f / 64.0f);
        tw[tid] = make_float2(cos1_hw(a), sin1_hw(a));
    }
    __syncthreads();

    const int k   = tid & 63;          // lane = k  (coalesced output)
    const int wv  = tid >> 6;
    const int n2a = (g << 3) + wv;
    const int n2b = n2a + 4;

    float Tr0 = 0.f, Ti0 = 0.f, Tr1 = 0.f, Ti1 = 0.f;
#pragma unroll 4
    for (int n1 = 0; n1 < 64; ++n1) {
        const float ya = YL[(n1 << 6) + n2a];   // wave-uniform -> broadcast
        const float yb = YL[(n1 << 6) + n2b];
        const float2 w = tw[(k * n1) & 63];     // e^{-i t}: (c, -s)
        Tr0 = fmaf(ya,  w.x, Tr0);
        Ti0 = fmaf(ya, -w.y, Ti0);
        Tr1 = fmaf(yb,  w.x, Tr1);
        Ti1 = fmaf(yb, -w.y, Ti1);
    }
    T[(b << 12) + (n2a << 6) + k] = pkrtz(Tr0, Ti0);
    T[(b << 12) + (n2b << 6) + k] = pkrtz(Tr1, Ti1);
}

// Pass 2: F[k,m] = sum_n2 T[k,n2] e^{-2pi i m n2/64};
// writes Frt[b][m][k], Fit[b][m][k] (transposed, f16) = A-operand layout.
__global__ __launch_bounds__(256)
void dft_pass2(const f16x2* __restrict__ T,
               _Float16* __restrict__ Frt, _Float16* __restrict__ Fit)
{
    __shared__ f16x2  TL[4096];     // [n2][k]
    __shared__ float2 tw[64];
    const int tid = threadIdx.x;
    const int b = blockIdx.x >> 3;
    const int g = blockIdx.x & 7;

    const float4* src = (const float4*)(T + (b << 12));
    float4* dst = (float4*)TL;
#pragma unroll
    for (int i = 0; i < 4; ++i) dst[tid + (i << 8)] = src[tid + (i << 8)];
    if (tid < 64) {
        const float a = (float)tid * (1.0f / 64.0f);
        tw[tid] = make_float2(cos1_hw(a), sin1_hw(a));
    }
    __syncthreads();

    const int k  = tid & 63;           // lane = k  (coalesced output)
    const int wv = tid >> 6;
    const int ma = (g << 3) + wv;
    const int mb = ma + 4;

    float Fr0 = 0.f, Fi0 = 0.f, Fr1 = 0.f, Fi1 = 0.f;
#pragma unroll 4
    for (int n2 = 0; n2 < 64; ++n2) {
        const f16x2 t = TL[(n2 << 6) + k];      // stride-1, 2-way (free)
        const float tr = (float)t[0];
        const float ti = (float)t[1];
        const float2 wa = tw[(ma * n2) & 63];   // wave-uniform
        const float2 wb = tw[(mb * n2) & 63];
        // (tr + i ti)(c - i s) = (tr c + ti s) + i(ti c - tr s)
        Fr0 = fmaf(tr, wa.x, Fr0); Fr0 = fmaf(ti,  wa.y, Fr0);
        Fi0 = fmaf(ti, wa.x, Fi0); Fi0 = fmaf(tr, -wa.y, Fi0);
        Fr1 = fmaf(tr, wb.x, Fr1); Fr1 = fmaf(ti,  wb.y, Fr1);
        Fi1 = fmaf(ti, wb.x, Fi1); Fi1 = fmaf(tr, -wb.y, Fi1);
    }
    const int oa = (b << 12) + (ma << 6) + k;
    const int ob = (b << 12) + (mb << 6) + k;
    Frt[oa] = (_Float16)Fr0;  Fit[oa] = (_Float16)Fi0;
    Frt[ob] = (_Float16)Fr1;  Fit[ob] = (_Float16)Fi1;
}

// Main: per point p, G[p,m] = sum_k F[k,m] E1[p,k]  (4 real MFMAs per
// complex product), then red = Re sum_m G[p,m] E2[p,m] on VALU.
// MFMA layout (proven): A[row=lrow][k=quad*8+j]; B[k][col=lrow];
// D: col=lrow(p), row=quad*4+reg (m within nt).
__global__ __launch_bounds__(1024, 4)
void fourier_interp_cplx(const _Float16* __restrict__ Frt,
                         const _Float16* __restrict__ Fit,
                         const float* __restrict__ xnew,
                         float* __restrict__ out)
{
    __shared__ float2 XY[2048];
    const int tid    = threadIdx.x;
    const int batch  = blockIdx.x >> 3;
    const int sgrp   = blockIdx.x & 7;       // 8 blocks per batch
    const int pbase  = (batch << 14) + (sgrp << 11);   // 2048 points

    XY[tid]        = ((const float2*)xnew)[pbase + tid];
    XY[tid + 1024] = ((const float2*)xnew)[pbase + tid + 1024];
    __syncthreads();

    const int lane = tid & 63;
    const int wv   = tid >> 6;               // 0..15
    const int quad = lane >> 4;
    const int lrow = lane & 15;

    // ---- hoist F^T fragments once per wave (covers all 4 segments) ----
    const _Float16* Fr = Frt + (batch << 12);
    const _Float16* Fi = Fit + (batch << 12);
    f16x8 Ar[4][2], Ai[4][2];
#pragma unroll
    for (int nt = 0; nt < 4; ++nt)
#pragma unroll
        for (int kt = 0; kt < 2; ++kt) {
            const int off = (((nt << 4) + lrow) << 6) + (kt << 5) + (quad << 3);
            Ar[nt][kt] = *(const f16x8*)(Fr + off);
            Ai[nt][kt] = *(const f16x8*)(Fi + off);
        }

#pragma unroll 1
    for (int mt = 0; mt < 8; ++mt) {
        // local point index of this lane's tile
        const int lpt = ((mt >> 1) << 9) + (wv << 5) + ((mt & 1) << 4);
        const float2 xv = XY[lpt + lrow];

        // rotation steps e^{2pi i x1} and e^{2pi i 2 x1}
        const float cs1 = cos1_hw(xv.x);
        const float sn1 = sin1_hw(xv.x);
        const float cs1b = fmaf(cs1, cs1, -(sn1 * sn1));
        const float sn1b = 2.0f * cs1 * sn1;

        f32x4 Gr[4], Gi[4];
#pragma unroll
        for (int nt = 0; nt < 4; ++nt) {
            Gr[nt] = (f32x4){0.f, 0.f, 0.f, 0.f};
            Gi[nt] = (f32x4){0.f, 0.f, 0.f, 0.f};
        }

#pragma unroll
        for (int kt = 0; kt < 2; ++kt) {
            // base frequency of this lane's 8-k run (never crosses k=32)
            const float fb = (float)((quad << 3) - (kt ? 32 : 0));
            float th = xv.x * fb;
            th -= floorf(th);                      // revolutions in [0,1)
            // two-seed split: even chain steps by rot^2, odd chain likewise
            float er0 = cos1_hw(th);
            float ei0 = sin1_hw(th);
            float er1 = fmaf(-ei0, sn1, er0 * cs1);
            float ei1 = fmaf( er0, sn1, ei0 * cs1);

            F16x8u ur, ui, un;                     // E1r, E1i, -E1i
#pragma unroll
            for (int jp = 0; jp < 4; ++jp) {
                ur.h[jp] = pkrtz(er0, er1);
                ui.h[jp] = pkrtz(ei0, ei1);
                un.h[jp] = pkrtz(-ei0, -ei1);
                if (jp < 3) {
                    const float e0 = fmaf(-ei0, sn1b, er0 * cs1b);
                    ei0 = fmaf(er0, sn1b, ei0 * cs1b);
                    er0 = e0;
                    const float e1 = fmaf(-ei1, sn1b, er1 * cs1b);
                    ei1 = fmaf(er1, sn1b, ei1 * cs1b);
                    er1 = e1;
                }
            }
#pragma unroll
            for (int nt = 0; nt < 4; ++nt) {
                Gr[nt] = __builtin_amdgcn_mfma_f32_16x16x32_f16(Ar[nt][kt], ur.v, Gr[nt], 0, 0, 0);
                Gr[nt] = __builtin_amdgcn_mfma_f32_16x16x32_f16(Ai[nt][kt], un.v, Gr[nt], 0, 0, 0);
                Gi[nt] = __builtin_amdgcn_mfma_f32_16x16x32_f16(Ar[nt][kt], ui.v, Gi[nt], 0, 0, 0);
                Gi[nt] = __builtin_amdgcn_mfma_f32_16x16x32_f16(Ai[nt][kt], ur.v, Gi[nt], 0, 0, 0);
            }
        }

        // ---- stage B: red = Re sum_m G[p,m] e^{2pi i x2 f(m)} ----
        const float cs2 = cos1_hw(xv.y);
        const float sn2 = sin1_hw(xv.y);
        float t16 = xv.y * 16.0f;
        t16 -= floorf(t16);
        const float c16 = cos1_hw(t16);
        const float s16 = sin1_hw(t16);
        const float cm32 = fmaf(c16, c16, -(s16 * s16));   // conj(rot16^2)
        const float sm32 = -2.0f * c16 * s16;

        float thA = xv.y * (float)(quad << 2);
        thA -= floorf(thA);
        const float erA = cos1_hw(thA);
        const float eiA = sin1_hw(thA);

        float br[4], bi[4];
        br[0] = erA;                            bi[0] = eiA;
        br[1] = fmaf(-eiA, s16, erA * c16);     bi[1] = fmaf(erA, s16, eiA * c16);
        br[2] = fmaf(-eiA, sm32, erA * cm32);   bi[2] = fmaf(erA, sm32, eiA * cm32);
        br[3] = fmaf(-bi[2], s16, br[2] * c16); bi[3] = fmaf(br[2], s16, bi[2] * c16);

        float red = 0.0f;
#pragma unroll
        for (int nt = 0; nt < 4; ++nt) {
            float er = br[nt];
            float ei = bi[nt];
#pragma unroll
            for (int reg = 0; reg < 4; ++reg) {
                red = fmaf(Gr[nt][reg],  er, red);
                red = fmaf(Gi[nt][reg], -ei, red);
                if (reg < 3) {
                    const float t2 = fmaf(-ei, sn2, er * cs2);
                    ei = fmaf(er, sn2, ei * cs2);
                    er = t2;
                }
            }
        }
        red += __shfl_xor(red, 16, 64);
        red += __shfl_xor(red, 32, 64);
        if (lane < 16)
            out[pbase + lpt + lane] = red * (1.0f / 4096.0f);
    }
}

extern "C" void kernel_launch(void* const* d_in, const int* in_sizes, int n_in,
                              void* d_out, int out_size, void* d_ws, size_t ws_size,
                              hipStream_t stream)
{
    const float* y    = (const float*)d_in[0];   // [32, 64, 64]
    const float* xnew = (const float*)d_in[1];   // [32, 128, 128, 2]
    float* out        = (float*)d_out;           // [32, 128, 128]

    // workspace layout (1 MiB used):
    //   T   : 32*64*64 half2  = 512 KiB
    //   Frt : 32*64*64 f16    = 256 KiB
    //   Fit : 32*64*64 f16    = 256 KiB
    f16x2*    T   = (f16x2*)d_ws;
    _Float16* Frt = (_Float16*)((char*)d_ws + (32 << 14));
    _Float16* Fit = Frt + (32 << 12);

    dft_pass1<<<256, 256, 0, stream>>>(y, T);
    dft_pass2<<<256, 256, 0, stream>>>(T, Frt, Fit);
    // DIAGNOSTIC: 4 identical launches of the idempotent main kernel.
    // dur_us inflation per extra launch = true kernel duration k_main.
    fourier_interp_cplx<<<256, 1024, 0, stream>>>(Frt, Fit, xnew, out);
    fourier_interp_cplx<<<256, 1024, 0, stream>>>(Frt, Fit, xnew, out);
    fourier_interp_cplx<<<256, 1024, 0, stream>>>(Frt, Fit, xnew, out);
    fourier_interp_cplx<<<256, 1024, 0, stream>>>(Frt, Fit, xnew, out);
}

// Round 7
// 99.514 us; speedup vs baseline: 1.5039x; 1.5039x over previous
//
#include <hip/hip_runtime.h>
#include <math.h>

typedef _Float16 f16x8 __attribute__((ext_vector_type(8)));
typedef _Float16 f16x2 __attribute__((ext_vector_type(2)));
typedef float    f32x4 __attribute__((ext_vector_type(4)));

union F16x8u { f16x8 v; f16x2 h[4]; };

// v_sin_f32 / v_cos_f32 take REVOLUTIONS: sin(2*pi*x) = v_sin(x).
__device__ __forceinline__ float cos1_hw(float x) { return __builtin_amdgcn_cosf(x); }
__device__ __forceinline__ float sin1_hw(float x) { return __builtin_amdgcn_sinf(x); }

// v_cvt_pkrtz_f16_f32 returns a __fp16 vector; bit-cast to our _Float16 pair.
__device__ __forceinline__ f16x2 pkrtz(float a, float b)
{
    return __builtin_bit_cast(f16x2, __builtin_amdgcn_cvt_pkrtz(a, b));
}

// ---------------------------------------------------------------------------
// ROUND 13 = SINGLE-DISPATCH FUSION.
// Round-12 diagnostic solved the timing model:
//   dur = 40.5us (ws-poison fill, fixed) + ~12us PER DISPATCH + kernel time
//   (k_main ~9us, DFT passes ~2us, old cot kernel ~29us; C solved to the
//    fill duration exactly, all 3 round-equations close to +-0.2us).
// So rounds 2-4 were null because 3 dispatches x 12us + fill dominated.
// This round: ONE kernel. Each block (1024 thr, grid 256 = 1 block/CU)
// redundantly computes its batch's 64x64 DFT in LDS (2 VALU passes, ~1.7us,
// 8x redundancy across sgrp blocks is free/parallel), writes F^T f16 at
// pitch 72 (16B-aligned rows, bank-spread), then runs the round-10 interp
// unchanged. No d_ws, no cross-block dependencies.
// ---------------------------------------------------------------------------

__global__ __launch_bounds__(1024, 4)
void fourier_fused(const float* __restrict__ y,
                   const float* __restrict__ xnew,
                   float* __restrict__ out)
{
    __shared__ float    YL[4096];        // y[batch], 16 KB
    __shared__ f16x2    TL[4096];        // T[n2][k] half2, 16 KB
    __shared__ _Float16 FrL[64 * 72];    // F^T re, pitch 72, 9 KB
    __shared__ _Float16 FiL[64 * 72];    // F^T im, 9 KB
    __shared__ float2   XY[2048];        // sample coords, 16 KB
    __shared__ float2   tw[64];          // (cos, sin)(2pi n/64)

    const int tid   = threadIdx.x;
    const int batch = blockIdx.x >> 3;
    const int sgrp  = blockIdx.x & 7;                 // 8 blocks per batch
    const int pbase = (batch << 14) + (sgrp << 11);   // 2048 points

    // ---- stage y + xnew + twiddles (one float4 each) ----
    ((float4*)YL)[tid] = ((const float4*)(y + (batch << 12)))[tid];
    ((float4*)XY)[tid] = ((const float4*)(xnew + ((size_t)pbase << 1)))[tid];
    if (tid < 64) {
        const float a = (float)tid * (1.0f / 64.0f);
        tw[tid] = make_float2(cos1_hw(a), sin1_hw(a));
    }
    __syncthreads();

    const int lane = tid & 63;
    const int wv   = tid >> 6;           // 0..15

    // ---- DFT pass A: T[n2][k] = sum_n1 y[n1,n2] e^{-2pi i k n1/64} ----
#pragma unroll
    for (int rep = 0; rep < 4; ++rep) {
        const int n2 = wv + (rep << 4);
        float Tr = 0.f, Ti = 0.f;
#pragma unroll 4
        for (int n1 = 0; n1 < 64; ++n1) {
            const float yv = YL[(n1 << 6) + n2];     // wave-uniform -> bcast
            const float2 w = tw[(lane * n1) & 63];   // e^{-it}: (c,-s)
            Tr = fmaf(yv,  w.x, Tr);
            Ti = fmaf(yv, -w.y, Ti);
        }
        TL[(n2 << 6) + lane] = pkrtz(Tr, Ti);
    }
    __syncthreads();

    // ---- DFT pass B: F^T[m][k] = sum_n2 T[n2][k] e^{-2pi i m n2/64} ----
#pragma unroll
    for (int rep = 0; rep < 4; ++rep) {
        const int m = wv + (rep << 4);
        float Fr = 0.f, Fi = 0.f;
#pragma unroll 4
        for (int n2 = 0; n2 < 64; ++n2) {
            const f16x2 t = TL[(n2 << 6) + lane];    // lane-stride-1
            const float tr = (float)t[0];
            const float ti = (float)t[1];
            const float2 w = tw[(m * n2) & 63];      // wave-uniform
            Fr = fmaf(tr, w.x, Fr); Fr = fmaf(ti,  w.y, Fr);
            Fi = fmaf(ti, w.x, Fi); Fi = fmaf(tr, -w.y, Fi);
        }
        FrL[m * 72 + lane] = (_Float16)Fr;
        FiL[m * 72 + lane] = (_Float16)Fi;
    }
    __syncthreads();

    const int quad = lane >> 4;
    const int lrow = lane & 15;

    // ---- hoist A-operand (F^T) fragments once per wave ----
    // row pitch 72 halfs = 144 B: 16B-aligned, rows spread 4 banks apart.
    f16x8 Ar[4][2], Ai[4][2];
#pragma unroll
    for (int nt = 0; nt < 4; ++nt)
#pragma unroll
        for (int kt = 0; kt < 2; ++kt) {
            const int off = ((nt << 4) + lrow) * 72 + (kt << 5) + (quad << 3);
            Ar[nt][kt] = *(const f16x8*)&FrL[off];
            Ai[nt][kt] = *(const f16x8*)&FiL[off];
        }

    // ---- interp: per point p, G[p,m] = sum_k F[k,m] E1[p,k] (MFMA),
    //      then red = Re sum_m G[p,m] E2[p,m] (VALU). Identical to r10.
#pragma unroll 1
    for (int mt = 0; mt < 8; ++mt) {
        const int lpt = ((mt >> 1) << 9) + (wv << 5) + ((mt & 1) << 4);
        const float2 xv = XY[lpt + lrow];

        // rotation steps e^{2pi i x1} and e^{2pi i 2 x1}
        const float cs1 = cos1_hw(xv.x);
        const float sn1 = sin1_hw(xv.x);
        const float cs1b = fmaf(cs1, cs1, -(sn1 * sn1));
        const float sn1b = 2.0f * cs1 * sn1;

        f32x4 Gr[4], Gi[4];
#pragma unroll
        for (int nt = 0; nt < 4; ++nt) {
            Gr[nt] = (f32x4){0.f, 0.f, 0.f, 0.f};
            Gi[nt] = (f32x4){0.f, 0.f, 0.f, 0.f};
        }

#pragma unroll
        for (int kt = 0; kt < 2; ++kt) {
            // base frequency of this lane's 8-k run (never crosses k=32)
            const float fb = (float)((quad << 3) - (kt ? 32 : 0));
            float th = xv.x * fb;
            th -= floorf(th);                      // revolutions in [0,1)
            // two-seed split: even chain steps by rot^2, odd chain likewise
            float er0 = cos1_hw(th);
            float ei0 = sin1_hw(th);
            float er1 = fmaf(-ei0, sn1, er0 * cs1);
            float ei1 = fmaf( er0, sn1, ei0 * cs1);

            F16x8u ur, ui, un;                     // E1r, E1i, -E1i
#pragma unroll
            for (int jp = 0; jp < 4; ++jp) {
                ur.h[jp] = pkrtz(er0, er1);
                ui.h[jp] = pkrtz(ei0, ei1);
                un.h[jp] = pkrtz(-ei0, -ei1);
                if (jp < 3) {
                    const float e0 = fmaf(-ei0, sn1b, er0 * cs1b);
                    ei0 = fmaf(er0, sn1b, ei0 * cs1b);
                    er0 = e0;
                    const float e1 = fmaf(-ei1, sn1b, er1 * cs1b);
                    ei1 = fmaf(er1, sn1b, ei1 * cs1b);
                    er1 = e1;
                }
            }
#pragma unroll
            for (int nt = 0; nt < 4; ++nt) {
                Gr[nt] = __builtin_amdgcn_mfma_f32_16x16x32_f16(Ar[nt][kt], ur.v, Gr[nt], 0, 0, 0);
                Gr[nt] = __builtin_amdgcn_mfma_f32_16x16x32_f16(Ai[nt][kt], un.v, Gr[nt], 0, 0, 0);
                Gi[nt] = __builtin_amdgcn_mfma_f32_16x16x32_f16(Ar[nt][kt], ui.v, Gi[nt], 0, 0, 0);
                Gi[nt] = __builtin_amdgcn_mfma_f32_16x16x32_f16(Ai[nt][kt], ur.v, Gi[nt], 0, 0, 0);
            }
        }

        // ---- stage B: red = Re sum_m G[p,m] e^{2pi i x2 f(m)} ----
        const float cs2 = cos1_hw(xv.y);
        const float sn2 = sin1_hw(xv.y);
        float t16 = xv.y * 16.0f;
        t16 -= floorf(t16);
        const float c16 = cos1_hw(t16);
        const float s16 = sin1_hw(t16);
        const float cm32 = fmaf(c16, c16, -(s16 * s16));   // conj(rot16^2)
        const float sm32 = -2.0f * c16 * s16;

        float thA = xv.y * (float)(quad << 2);
        thA -= floorf(thA);
        const float erA = cos1_hw(thA);
        const float eiA = sin1_hw(thA);

        float br[4], bi[4];
        br[0] = erA;                            bi[0] = eiA;
        br[1] = fmaf(-eiA, s16, erA * c16);     bi[1] = fmaf(erA, s16, eiA * c16);
        br[2] = fmaf(-eiA, sm32, erA * cm32);   bi[2] = fmaf(erA, sm32, eiA * cm32);
        br[3] = fmaf(-bi[2], s16, br[2] * c16); bi[3] = fmaf(br[2], s16, bi[2] * c16);

        float red = 0.0f;
#pragma unroll
        for (int nt = 0; nt < 4; ++nt) {
            float er = br[nt];
            float ei = bi[nt];
#pragma unroll
            for (int reg = 0; reg < 4; ++reg) {
                red = fmaf(Gr[nt][reg],  er, red);
                red = fmaf(Gi[nt][reg], -ei, red);
                if (reg < 3) {
                    const float t2 = fmaf(-ei, sn2, er * cs2);
                    ei = fmaf(er, sn2, ei * cs2);
                    er = t2;
                }
            }
        }
        red += __shfl_xor(red, 16, 64);
        red += __shfl_xor(red, 32, 64);
        if (lane < 16)
            out[pbase + lpt + lane] = red * (1.0f / 4096.0f);
    }
}

extern "C" void kernel_launch(void* const* d_in, const int* in_sizes, int n_in,
                              void* d_out, int out_size, void* d_ws, size_t ws_size,
                              hipStream_t stream)
{
    const float* y    = (const float*)d_in[0];   // [32, 64, 64]
    const float* xnew = (const float*)d_in[1];   // [32, 128, 128, 2]
    float* out        = (float*)d_out;           // [32, 128, 128]

    // ONE dispatch: 32 batches x 8 segment-groups = 256 blocks = 1 per CU.
    fourier_fused<<<256, 1024, 0, stream>>>(y, xnew, out);
}

// Round 8
// 76.848 us; speedup vs baseline: 1.9475x; 1.2949x over previous
//
#include <hip/hip_runtime.h>
#include <math.h>

typedef _Float16 f16x8 __attribute__((ext_vector_type(8)));
typedef _Float16 f16x2 __attribute__((ext_vector_type(2)));
typedef float    f32x4 __attribute__((ext_vector_type(4)));

union F16x8u { f16x8 v; f16x2 h[4]; };

// v_sin_f32 / v_cos_f32 take REVOLUTIONS: sin(2*pi*x) = v_sin(x).
__device__ __forceinline__ float cos1_hw(float x) { return __builtin_amdgcn_cosf(x); }
__device__ __forceinline__ float sin1_hw(float x) { return __builtin_amdgcn_sinf(x); }

// v_cvt_pkrtz_f16_f32 returns a __fp16 vector; bit-cast to our _Float16 pair.
__device__ __forceinline__ f16x2 pkrtz(float a, float b)
{
    return __builtin_bit_cast(f16x2, __builtin_amdgcn_cvt_pkrtz(a, b));
}

// ---------------------------------------------------------------------------
// ROUND 14 = MFMA-DFT FUSION.
// Round-13 counters (first real profile): fused kernel 54.3us, MfmaUtil 12.5,
// VALUBusy 63.7, bank-conflicts 1.28M. The VALU-DFT (770 ds_read + ~3400
// VALU inst/thread, 16 waves sharing one LDS pipe) was ~35us of the 54 --
// "redundant DFT is free" was wrong at the implementation level.
// This round the DFT runs on the matrix pipe: T = W*Y, F = T*W2 as MFMA
// (16 waves x 1 tile: 12 MFMA + ~60 LDS ops per wave). Interp stage is
// byte-identical to round 13. Single dispatch kept (per-dispatch overhead
// measured small; timed constant = 40.5us ws-poison fill).
// Predicted: kernel 54.3 -> 18-23us, dur_us 99.5 -> 63-68.
// ---------------------------------------------------------------------------

__global__ __launch_bounds__(1024, 4)
void fourier_fused(const float* __restrict__ y,
                   const float* __restrict__ xnew,
                   float* __restrict__ out)
{
    __shared__ _Float16 Yt [64 * 72];    // Y^T f16: Yt[n2][n1], pitch 72 (144B rows, 16B-aligned)
    __shared__ _Float16 Trl[64 * 72];    // T re: Trl[k][n2]
    __shared__ _Float16 Til[64 * 72];    // T im
    __shared__ _Float16 FrL[64 * 72];    // F^T re: FrL[m][k]
    __shared__ _Float16 FiL[64 * 72];    // F^T im
    __shared__ float2   XY[2048];        // sample coords
    __shared__ float2   tw[64];          // (cos, sin)(2pi n/64)

    const int tid   = threadIdx.x;
    const int batch = blockIdx.x >> 3;
    const int sgrp  = blockIdx.x & 7;                 // 8 blocks per batch
    const int pbase = (batch << 14) + (sgrp << 11);   // 2048 points

    // ---- stage xnew + y (transposed f16) + twiddles ----
    ((float4*)XY)[tid] = ((const float4*)(xnew + ((size_t)pbase << 1)))[tid];
    {
        const float4 v = ((const float4*)(y + (batch << 12)))[tid];
        const int n1 = tid >> 4;            // row of y
        const int n2 = (tid & 15) << 2;     // col base
        Yt[(n2 + 0) * 72 + n1] = (_Float16)v.x;
        Yt[(n2 + 1) * 72 + n1] = (_Float16)v.y;
        Yt[(n2 + 2) * 72 + n1] = (_Float16)v.z;
        Yt[(n2 + 3) * 72 + n1] = (_Float16)v.w;
    }
    if (tid < 64) {
        const float a = (float)tid * (1.0f / 64.0f);
        tw[tid] = make_float2(cos1_hw(a), sin1_hw(a));
    }
    __syncthreads();

    const int lane = tid & 63;
    const int wv   = tid >> 6;           // 0..15
    const int quad = lane >> 4;
    const int lrow = lane & 15;

    // ---- DFT pass A (MFMA): T[k][n2] = sum_n1 e^{-2pi i k n1/64} Y[n1][n2]
    // wave (rt,ct) owns tile k in rt*16+0..15, n2 in ct*16+0..15.
    // A-frag: lane holds W[row=rt*16+lrow][n1=kt*32+quad*8+j] from tw.
    // B-frag: lane holds Y[n1=kt*32+quad*8+j][n2=ct*16+lrow] = Yt row read.
    {
        const int rt   = wv >> 2;
        const int ct   = wv & 3;
        const int krow = (rt << 4) + lrow;
        f32x4 Tr = (f32x4){0.f, 0.f, 0.f, 0.f};
        f32x4 Ti = (f32x4){0.f, 0.f, 0.f, 0.f};
#pragma unroll
        for (int kt = 0; kt < 2; ++kt) {
            const int n1b = (kt << 5) + (quad << 3);
            F16x8u cf, sn;                      // cos, -sin  (W = c - i s)
#pragma unroll
            for (int jp = 0; jp < 4; ++jp) {
                const float2 wa = tw[(krow * (n1b + 2 * jp    )) & 63];
                const float2 wb = tw[(krow * (n1b + 2 * jp + 1)) & 63];
                cf.h[jp] = pkrtz(wa.x, wb.x);
                sn.h[jp] = pkrtz(-wa.y, -wb.y);
            }
            const f16x8 yf = *(const f16x8*)&Yt[((ct << 4) + lrow) * 72 + n1b];
            Tr = __builtin_amdgcn_mfma_f32_16x16x32_f16(cf.v, yf, Tr, 0, 0, 0);
            Ti = __builtin_amdgcn_mfma_f32_16x16x32_f16(sn.v, yf, Ti, 0, 0, 0);
        }
        // D: lane holds T[k = rt*16 + quad*4 + reg][n2 = ct*16 + lrow]
#pragma unroll
        for (int reg = 0; reg < 4; ++reg) {
            const int k = (rt << 4) + (quad << 2) + reg;
            Trl[k * 72 + (ct << 4) + lrow] = (_Float16)Tr[reg];
            Til[k * 72 + (ct << 4) + lrow] = (_Float16)Ti[reg];
        }
    }
    __syncthreads();

    // ---- DFT pass B (MFMA): F[k][m] = sum_n2 T[k][n2] e^{-2pi i m n2/64},
    // computed as F^T tiles: D[row=m][col=k] = sum_n2 W2^T[m][n2] T^T[n2][k].
    // F = (c - i s)(Tr + i Ti):  Fr = c*Tr + s*Ti ;  Fi = c*Ti - s*Tr.
    {
        const int mt2 = wv >> 2;
        const int ct2 = wv & 3;
        const int mrow = (mt2 << 4) + lrow;
        f32x4 Fr = (f32x4){0.f, 0.f, 0.f, 0.f};
        f32x4 Fi = (f32x4){0.f, 0.f, 0.f, 0.f};
#pragma unroll
        for (int kt = 0; kt < 2; ++kt) {
            const int n2b = (kt << 5) + (quad << 3);
            F16x8u cf, sf, sn;
#pragma unroll
            for (int jp = 0; jp < 4; ++jp) {
                const float2 wa = tw[(mrow * (n2b + 2 * jp    )) & 63];
                const float2 wb = tw[(mrow * (n2b + 2 * jp + 1)) & 63];
                cf.h[jp] = pkrtz(wa.x, wb.x);
                sf.h[jp] = pkrtz(wa.y, wb.y);
                sn.h[jp] = pkrtz(-wa.y, -wb.y);
            }
            const f16x8 btr = *(const f16x8*)&Trl[((ct2 << 4) + lrow) * 72 + n2b];
            const f16x8 bti = *(const f16x8*)&Til[((ct2 << 4) + lrow) * 72 + n2b];
            Fr = __builtin_amdgcn_mfma_f32_16x16x32_f16(cf.v, btr, Fr, 0, 0, 0);
            Fr = __builtin_amdgcn_mfma_f32_16x16x32_f16(sf.v, bti, Fr, 0, 0, 0);
            Fi = __builtin_amdgcn_mfma_f32_16x16x32_f16(cf.v, bti, Fi, 0, 0, 0);
            Fi = __builtin_amdgcn_mfma_f32_16x16x32_f16(sn.v, btr, Fi, 0, 0, 0);
        }
        // D: lane holds F^T[m = mt2*16 + quad*4 + reg][k = ct2*16 + lrow]
#pragma unroll
        for (int reg = 0; reg < 4; ++reg) {
            const int m = (mt2 << 4) + (quad << 2) + reg;
            FrL[m * 72 + (ct2 << 4) + lrow] = (_Float16)Fr[reg];
            FiL[m * 72 + (ct2 << 4) + lrow] = (_Float16)Fi[reg];
        }
    }
    __syncthreads();

    // ---- hoist A-operand (F^T) fragments once per wave ----
    f16x8 Ar[4][2], Ai[4][2];
#pragma unroll
    for (int nt = 0; nt < 4; ++nt)
#pragma unroll
        for (int kt = 0; kt < 2; ++kt) {
            const int off = ((nt << 4) + lrow) * 72 + (kt << 5) + (quad << 3);
            Ar[nt][kt] = *(const f16x8*)&FrL[off];
            Ai[nt][kt] = *(const f16x8*)&FiL[off];
        }

    // ---- interp: per point p, G[p,m] = sum_k F[k,m] E1[p,k] (MFMA),
    //      then red = Re sum_m G[p,m] E2[p,m] (VALU). Identical to r13.
#pragma unroll 1
    for (int mt = 0; mt < 8; ++mt) {
        const int lpt = ((mt >> 1) << 9) + (wv << 5) + ((mt & 1) << 4);
        const float2 xv = XY[lpt + lrow];

        // rotation steps e^{2pi i x1} and e^{2pi i 2 x1}
        const float cs1 = cos1_hw(xv.x);
        const float sn1 = sin1_hw(xv.x);
        const float cs1b = fmaf(cs1, cs1, -(sn1 * sn1));
        const float sn1b = 2.0f * cs1 * sn1;

        f32x4 Gr[4], Gi[4];
#pragma unroll
        for (int nt = 0; nt < 4; ++nt) {
            Gr[nt] = (f32x4){0.f, 0.f, 0.f, 0.f};
            Gi[nt] = (f32x4){0.f, 0.f, 0.f, 0.f};
        }

#pragma unroll
        for (int kt = 0; kt < 2; ++kt) {
            // base frequency of this lane's 8-k run (never crosses k=32)
            const float fb = (float)((quad << 3) - (kt ? 32 : 0));
            float th = xv.x * fb;
            th -= floorf(th);                      // revolutions in [0,1)
            // two-seed split: even chain steps by rot^2, odd chain likewise
            float er0 = cos1_hw(th);
            float ei0 = sin1_hw(th);
            float er1 = fmaf(-ei0, sn1, er0 * cs1);
            float ei1 = fmaf( er0, sn1, ei0 * cs1);

            F16x8u ur, ui, un;                     // E1r, E1i, -E1i
#pragma unroll
            for (int jp = 0; jp < 4; ++jp) {
                ur.h[jp] = pkrtz(er0, er1);
                ui.h[jp] = pkrtz(ei0, ei1);
                un.h[jp] = pkrtz(-ei0, -ei1);
                if (jp < 3) {
                    const float e0 = fmaf(-ei0, sn1b, er0 * cs1b);
                    ei0 = fmaf(er0, sn1b, ei0 * cs1b);
                    er0 = e0;
                    const float e1 = fmaf(-ei1, sn1b, er1 * cs1b);
                    ei1 = fmaf(er1, sn1b, ei1 * cs1b);
                    er1 = e1;
                }
            }
#pragma unroll
            for (int nt = 0; nt < 4; ++nt) {
                Gr[nt] = __builtin_amdgcn_mfma_f32_16x16x32_f16(Ar[nt][kt], ur.v, Gr[nt], 0, 0, 0);
                Gr[nt] = __builtin_amdgcn_mfma_f32_16x16x32_f16(Ai[nt][kt], un.v, Gr[nt], 0, 0, 0);
                Gi[nt] = __builtin_amdgcn_mfma_f32_16x16x32_f16(Ar[nt][kt], ui.v, Gi[nt], 0, 0, 0);
                Gi[nt] = __builtin_amdgcn_mfma_f32_16x16x32_f16(Ai[nt][kt], ur.v, Gi[nt], 0, 0, 0);
            }
        }

        // ---- stage B: red = Re sum_m G[p,m] e^{2pi i x2 f(m)} ----
        const float cs2 = cos1_hw(xv.y);
        const float sn2 = sin1_hw(xv.y);
        float t16 = xv.y * 16.0f;
        t16 -= floorf(t16);
        const float c16 = cos1_hw(t16);
        const float s16 = sin1_hw(t16);
        const float cm32 = fmaf(c16, c16, -(s16 * s16));   // conj(rot16^2)
        const float sm32 = -2.0f * c16 * s16;

        float thA = xv.y * (float)(quad << 2);
        thA -= floorf(thA);
        const float erA = cos1_hw(thA);
        const float eiA = sin1_hw(thA);

        float br[4], bi[4];
        br[0] = erA;                            bi[0] = eiA;
        br[1] = fmaf(-eiA, s16, erA * c16);     bi[1] = fmaf(erA, s16, eiA * c16);
        br[2] = fmaf(-eiA, sm32, erA * cm32);   bi[2] = fmaf(erA, sm32, eiA * cm32);
        br[3] = fmaf(-bi[2], s16, br[2] * c16); bi[3] = fmaf(br[2], s16, bi[2] * c16);

        float red = 0.0f;
#pragma unroll
        for (int nt = 0; nt < 4; ++nt) {
            float er = br[nt];
            float ei = bi[nt];
#pragma unroll
            for (int reg = 0; reg < 4; ++reg) {
                red = fmaf(Gr[nt][reg],  er, red);
                red = fmaf(Gi[nt][reg], -ei, red);
                if (reg < 3) {
                    const float t2 = fmaf(-ei, sn2, er * cs2);
                    ei = fmaf(er, sn2, ei * cs2);
                    er = t2;
                }
            }
        }
        red += __shfl_xor(red, 16, 64);
        red += __shfl_xor(red, 32, 64);
        if (lane < 16)
            out[pbase + lpt + lane] = red * (1.0f / 4096.0f);
    }
}

extern "C" void kernel_launch(void* const* d_in, const int* in_sizes, int n_in,
                              void* d_out, int out_size, void* d_ws, size_t ws_size,
                              hipStream_t stream)
{
    const float* y    = (const float*)d_in[0];   // [32, 64, 64]
    const float* xnew = (const float*)d_in[1];   // [32, 128, 128, 2]
    float* out        = (float*)d_out;           // [32, 128, 128]

    // ONE dispatch: 32 batches x 8 segment-groups = 256 blocks = 1 per CU.
    fourier_fused<<<256, 1024, 0, stream>>>(y, xnew, out);
}